// Round 11
// baseline (7115.167 us; speedup 1.0000x reference)
//
#include <hip/hip_runtime.h>
#include <hip/hip_bf16.h>
#include <stdint.h>

typedef __hip_bfloat16 bf16_t;
typedef __attribute__((ext_vector_type(8))) short bf16x8;
typedef __attribute__((ext_vector_type(4))) float f32x4;

#define MU_DT 0.01f

__device__ inline void gload_lds16(const void* g, void* lds) {
  __builtin_amdgcn_global_load_lds((const __attribute__((address_space(1))) void*)g,
                                   (__attribute__((address_space(3))) void*)lds, 16, 0, 0);
}

// mode: 0 = forward tanh layer, 1 = forward identity (last) layer,
//       2 = backward layer 0 (e0 == mu0), 3 = backward layer >0
struct GemmLayer {
  const bf16_t* A;    // (512 x K) bf16, row-major
  const bf16_t* Bt;   // (N x K) bf16, row-major  ("B^T layout" operand)
  const float*  X;    // fwd: mu_{l+1} or img (512 x N); bwd: mu_l (512 x N)
  const float*  E;    // bwd l>0: e_l (512 x N); else unused
  float*        O1;   // fwd: e_{l+1} out (stride ostride); bwd: mu_l out (f32)
  bf16_t*       O2;   // fwd: G_l out (bf16, 512 x N); bwd: mub_l out (bf16)
  int K, N, ostride, mode;
};

struct GemmArgs {
  GemmLayer L[3];
  int start1, start2;     // flat block-id starts of layer 1 and layer 2
  int tn0, tn1, tn2;      // tiles along N per layer
};

// R11: STAGED-BYTES reduction. Model from R8/R10: global_load_lds return
// path ~16 B/cy/CU is the binding resource (time ~ staged bytes: R8 768MB
// ->85us, R10 1024MB->102us). So: stage ONLY B (weights) via gload_lds;
// A fragments are loaded straight from global into VGPRs (per-wave-private
// 16-row x 64B segments, L1/L2-served vector-load path, which is idle).
// Staged bytes per block-step: 24KB -> 16KB. A-regs for step kt+1 are
// issued at the TOP of step kt -> latency hides under the whole step and
// __syncthreads' vmcnt(0) drain covers them.
// Everything else = R8 (best known): BM=64 x BN=128, BK=64, 8 waves,
// wave 32x32 of 16x16x32 MFMA, B dbuf 2x16KB, one __syncthreads/K-step.
//
// Grid mapping: local = tm*tilesN + tn (tn FASTEST). tilesN multiple of 8
// -> the 8 m-tile sharers of B-panel tn are congruent mod 8 -> SAME XCD
// (round-robin dispatch) -> B fetched once per L2. (R5 regression guard.)
//
// B swizzle: LDS rows 128B = 8 x 16B slots, slot ^= (row&7), applied on
// the global SOURCE address (LDS linear for gload_lds) and on ds_read
// (rule #21). k-bijection: a and b frags both use k = kk*32 + hi*8.
__global__ __launch_bounds__(512) void gemm_merged(GemmArgs args) {
  __shared__ __align__(16) bf16_t Bs[2 * 128 * 64];   // 2 x 16 KiB

  const int bid = blockIdx.x;
  int l, local, tilesN;
  if (bid >= args.start2)      { l = 2; local = bid - args.start2; tilesN = args.tn2; }
  else if (bid >= args.start1) { l = 1; local = bid - args.start1; tilesN = args.tn1; }
  else                         { l = 0; local = bid;               tilesN = args.tn0; }
  const GemmLayer Lr = args.L[l];
  const int tm = local / tilesN;
  const int tn = local % tilesN;
  const int K = Lr.K;
  const int rowBase = tm * 64;
  const int colBase = tn * 128;

  const int tid  = threadIdx.x;        // 0..511
  const int lane = tid & 63;
  const int wv   = tid >> 6;           // 0..7
  const int wrM  = wv >> 2;            // 0..1 -> 32-row band
  const int wcN  = wv & 3;             // 0..3 -> 32-col band
  const int lo   = lane & 15, hi = lane >> 4;

  f32x4 acc[2][2];
#pragma unroll
  for (int m = 0; m < 2; ++m)
#pragma unroll
    for (int n = 0; n < 2; ++n)
      acc[m][n] = f32x4{0.f, 0.f, 0.f, 0.f};

  char* BsB = (char*)Bs;   // halves at +0 / +16384

  // ---- B staging precompute: per 16B-chunk c -> (row = c>>3, slot = c&7) ----
  // B tile: 128x64 bf16 = 1024 chunks (2/thread).
  const bf16_t* pB[2];
#pragma unroll
  for (int j = 0; j < 2; ++j) {
    const int c = j * 512 + tid;
    const int r = c >> 3, sw = (c & 7) ^ (r & 7);
    pB[j] = Lr.Bt + (size_t)(colBase + r) * K + sw * 8;
  }

  // ---- A direct-from-global fragment pointers (per wave, registers) ----
  // a[m][kk]: lane reads A[rowBase + wrM*32 + m*16 + lo][kt*64 + kk*32 + hi*8 ..+8]
  const bf16_t* pa00 = Lr.A + (size_t)(rowBase + wrM * 32 +  0 + lo) * K +  0 + hi * 8;
  const bf16_t* pa01 = Lr.A + (size_t)(rowBase + wrM * 32 +  0 + lo) * K + 32 + hi * 8;
  const bf16_t* pa10 = Lr.A + (size_t)(rowBase + wrM * 32 + 16 + lo) * K +  0 + hi * 8;
  const bf16_t* pa11 = Lr.A + (size_t)(rowBase + wrM * 32 + 16 + lo) * K + 32 + hi * 8;

  // ---- B read-side swizzled byte offsets ----
  int boff[2][2];
#pragma unroll
  for (int n = 0; n < 2; ++n) {
    const int row = wcN * 32 + n * 16 + lo;
#pragma unroll
    for (int kk = 0; kk < 2; ++kk)
      boff[n][kk] = row * 128 + (((kk * 4 + hi) ^ (row & 7)) << 4);
  }

  const int waveB = wv * 1024;
  const int nkt = K >> 6;   // >= 16 for all layers

  // prologue: stage B tile 0 into half 0; load A frags for kt=0
  gload_lds16(pB[0], BsB + waveB);
  gload_lds16(pB[1], BsB + 8192 + waveB);
  bf16x8 a00 = *(const bf16x8*)pa00;
  bf16x8 a01 = *(const bf16x8*)pa01;
  bf16x8 a10 = *(const bf16x8*)pa10;
  bf16x8 a11 = *(const bf16x8*)pa11;
  __syncthreads();

  int cur = 0;   // byte offset of current half (0 / 16384)
  for (int kt = 0; kt < nkt; ++kt) {
    bf16x8 n00, n01, n10, n11;
    if (kt + 1 < nkt) {
      const int ke = (kt + 1) * 64;
      const int nxt = cur ^ 16384;
      // issue next B-stage and next A-reg loads FIRST (hide under this step)
      gload_lds16(pB[0] + ke, BsB + nxt + waveB);
      gload_lds16(pB[1] + ke, BsB + nxt + 8192 + waveB);
      n00 = *(const bf16x8*)(pa00 + ke);
      n01 = *(const bf16x8*)(pa01 + ke);
      n10 = *(const bf16x8*)(pa10 + ke);
      n11 = *(const bf16x8*)(pa11 + ke);
    }

    bf16x8 b[2][2];
#pragma unroll
    for (int n = 0; n < 2; ++n)
#pragma unroll
      for (int kk = 0; kk < 2; ++kk)
        b[n][kk] = *(const bf16x8*)(BsB + cur + boff[n][kk]);

    acc[0][0] = __builtin_amdgcn_mfma_f32_16x16x32_bf16(a00, b[0][0], acc[0][0], 0, 0, 0);
    acc[0][1] = __builtin_amdgcn_mfma_f32_16x16x32_bf16(a00, b[1][0], acc[0][1], 0, 0, 0);
    acc[1][0] = __builtin_amdgcn_mfma_f32_16x16x32_bf16(a10, b[0][0], acc[1][0], 0, 0, 0);
    acc[1][1] = __builtin_amdgcn_mfma_f32_16x16x32_bf16(a10, b[1][0], acc[1][1], 0, 0, 0);
    acc[0][0] = __builtin_amdgcn_mfma_f32_16x16x32_bf16(a01, b[0][1], acc[0][0], 0, 0, 0);
    acc[0][1] = __builtin_amdgcn_mfma_f32_16x16x32_bf16(a01, b[1][1], acc[0][1], 0, 0, 0);
    acc[1][0] = __builtin_amdgcn_mfma_f32_16x16x32_bf16(a11, b[0][1], acc[1][0], 0, 0, 0);
    acc[1][1] = __builtin_amdgcn_mfma_f32_16x16x32_bf16(a11, b[1][1], acc[1][1], 0, 0, 0);

    if (kt + 1 < nkt) {
      __syncthreads();   // drains vmcnt (B-stage + A-regs) + lgkm
      a00 = n00; a01 = n01; a10 = n10; a11 = n11;
      cur ^= 16384;
    }
  }

  // epilogue — C/D layout: col = lane&15, row = (lane>>4)*4 + reg
  const int N = Lr.N;
#pragma unroll
  for (int m = 0; m < 2; ++m) {
#pragma unroll
    for (int n = 0; n < 2; ++n) {
#pragma unroll
      for (int r = 0; r < 4; ++r) {
        const int row = rowBase + wrM * 32 + m * 16 + hi * 4 + r;
        const int col = colBase + wcN * 32 + n * 16 + lo;
        const float v = acc[m][n][r];
        const size_t iN = (size_t)row * N + col;
        const size_t iO = (size_t)row * Lr.ostride + col;
        if (Lr.mode == 0) {
          const float mu = Lr.X[iN];
          const float t  = tanhf(v);
          const float e  = mu - t;
          Lr.O1[iO] = e;
          Lr.O2[iN] = __float2bfloat16(e * (1.0f - t * t));
        } else if (Lr.mode == 1) {
          const float e = Lr.X[iN] - v;
          Lr.O1[iO] = e;
          Lr.O2[iN] = __float2bfloat16(e);
        } else if (Lr.mode == 2) {
          const float mu = Lr.X[iN];
          const float nv = mu + MU_DT * (v - mu);
          Lr.O1[iN] = nv;
          Lr.O2[iN] = __float2bfloat16(nv);
        } else {
          const float mu = Lr.X[iN];
          const float e  = Lr.E[iN];
          const float nv = mu + MU_DT * (v - e);
          Lr.O1[iN] = nv;
          Lr.O2[iN] = __float2bfloat16(nv);
        }
      }
    }
  }
}

// convert W (R x C f32) -> Wb (R x C bf16) and WTb (C x R bf16)
__global__ void prep_weight(const float* __restrict__ W, bf16_t* __restrict__ Wb,
                            bf16_t* __restrict__ WTb, int R, int C) {
  __shared__ bf16_t t[64][65];
  const int tx = threadIdx.x, ty = threadIdx.y;  // (64,4)
  const int c0 = blockIdx.x * 64, r0 = blockIdx.y * 64;
  for (int rr = ty; rr < 64; rr += 4) {
    const float v = W[(size_t)(r0 + rr) * C + c0 + tx];
    const bf16_t b = __float2bfloat16(v);
    Wb[(size_t)(r0 + rr) * C + c0 + tx] = b;
    t[rr][tx] = b;
  }
  __syncthreads();
  for (int rr = ty; rr < 64; rr += 4) {
    WTb[(size_t)(c0 + rr) * R + r0 + tx] = t[tx][rr];
  }
}

__global__ void copy_cast(const float* __restrict__ in, float* __restrict__ of,
                          bf16_t* __restrict__ ob, int n) {
  const int i = blockIdx.x * blockDim.x + threadIdx.x;
  if (i < n) {
    const float v = in[i];
    of[i] = v;
    ob[i] = __float2bfloat16(v);
  }
}

__global__ void copy_e0(const float* __restrict__ mu0, float* __restrict__ out) {
  const int i = blockIdx.x * blockDim.x + threadIdx.x;
  if (i < 512 * 1024) {
    const int b = i >> 10, j = i & 1023;
    out[(size_t)b * 12288 + j] = mu0[i];
  }
}

extern "C" void kernel_launch(void* const* d_in, const int* in_sizes, int n_in,
                              void* d_out, int out_size, void* d_ws, size_t ws_size,
                              hipStream_t stream) {
  const float* img  = (const float*)d_in[0];
  const float* mu0i = (const float*)d_in[1];
  const float* mu1i = (const float*)d_in[2];
  const float* mu2i = (const float*)d_in[3];
  const float* W0   = (const float*)d_in[4];
  const float* W1   = (const float*)d_in[5];
  const float* W2   = (const float*)d_in[6];
  float* out = (float*)d_out;
  const int n_iters = 20;  // fixed by setup_inputs

  // ---- workspace carve (all offsets 256B aligned) ----
  char* p = (char*)d_ws;
  auto alloc = [&](size_t bytes) -> char* {
    char* r = p;
    p += (bytes + 255) & ~(size_t)255;
    return r;
  };
  bf16_t* Wb0 = (bf16_t*)alloc((size_t)1024 * 4096 * 2);
  bf16_t* Wb1 = (bf16_t*)alloc((size_t)4096 * 4096 * 2);
  bf16_t* Wb2 = (bf16_t*)alloc((size_t)4096 * 3072 * 2);
  bf16_t* WT0 = (bf16_t*)alloc((size_t)4096 * 1024 * 2);
  bf16_t* WT1 = (bf16_t*)alloc((size_t)4096 * 4096 * 2);
  bf16_t* WT2 = (bf16_t*)alloc((size_t)3072 * 4096 * 2);
  float*  mu0 = (float*)alloc((size_t)512 * 1024 * 4);
  float*  mu1 = (float*)alloc((size_t)512 * 4096 * 4);
  float*  mu2 = (float*)alloc((size_t)512 * 4096 * 4);
  bf16_t* mb0 = (bf16_t*)alloc((size_t)512 * 1024 * 2);
  bf16_t* mb1 = (bf16_t*)alloc((size_t)512 * 4096 * 2);
  bf16_t* mb2 = (bf16_t*)alloc((size_t)512 * 4096 * 2);
  float*  e1  = (float*)alloc((size_t)512 * 4096 * 4);
  float*  e2  = (float*)alloc((size_t)512 * 4096 * 4);
  float*  e3  = (float*)alloc((size_t)512 * 3072 * 4);
  bf16_t* G0  = (bf16_t*)alloc((size_t)512 * 4096 * 2);
  bf16_t* G1  = (bf16_t*)alloc((size_t)512 * 4096 * 2);
  bf16_t* G2  = (bf16_t*)alloc((size_t)512 * 3072 * 2);
  (void)ws_size;

  // ---- prep: weights + mus ----
  dim3 tb(64, 4);
  prep_weight<<<dim3(4096 / 64, 1024 / 64), tb, 0, stream>>>(W0, Wb0, WT0, 1024, 4096);
  prep_weight<<<dim3(4096 / 64, 4096 / 64), tb, 0, stream>>>(W1, Wb1, WT1, 4096, 4096);
  prep_weight<<<dim3(3072 / 64, 4096 / 64), tb, 0, stream>>>(W2, Wb2, WT2, 4096, 3072);
  copy_cast<<<(512 * 1024 + 255) / 256, 256, 0, stream>>>(mu0i, mu0, mb0, 512 * 1024);
  copy_cast<<<(512 * 4096 + 255) / 256, 256, 0, stream>>>(mu1i, mu1, mb1, 512 * 4096);
  copy_cast<<<(512 * 4096 + 255) / 256, 256, 0, stream>>>(mu2i, mu2, mb2, 512 * 4096);

  // ---- GEMM argument blocks (BM=64 -> 8 M-tiles) ----
  // forward: h_l = mu_l @ W_l  -> epilogue produces e_{l+1}, G_l
  GemmArgs fa;
  fa.L[0] = { mb0, WT0, mu1, nullptr, e1, G0, 1024, 4096, 4096, 0 };
  fa.L[1] = { mb1, WT1, mu2, nullptr, e2, G1, 4096, 4096, 4096, 0 };
  fa.L[2] = { mb2, WT2, img, nullptr, e3, G2, 4096, 3072, 3072, 1 };
  fa.tn0 = 32; fa.tn1 = 32; fa.tn2 = 24;
  fa.start1 = 8 * 32;             // 256
  fa.start2 = fa.start1 + 8 * 32; // 512
  const int fwdBlocks = fa.start2 + 8 * 24;  // 704

  GemmArgs faF = fa;  // final pass: write errs straight into d_out (stride 12288)
  faF.L[0].O1 = out + 1024; faF.L[0].ostride = 12288;
  faF.L[1].O1 = out + 5120; faF.L[1].ostride = 12288;
  faF.L[2].O1 = out + 9216; faF.L[2].ostride = 12288;

  // backward: back_l = G_l @ W_l^T -> epilogue updates mu_l (f32 + bf16)
  GemmArgs ba;
  ba.L[0] = { G0, Wb0, mu0, nullptr, mu0, mb0, 4096, 1024, 1024, 2 };
  ba.L[1] = { G1, Wb1, mu1, e1,      mu1, mb1, 4096, 4096, 4096, 3 };
  ba.L[2] = { G2, Wb2, mu2, e2,      mu2, mb2, 3072, 4096, 4096, 3 };
  ba.tn0 = 8; ba.tn1 = 32; ba.tn2 = 32;
  ba.start1 = 8 * 8;              // 64
  ba.start2 = ba.start1 + 8 * 32; // 320
  const int bwdBlocks = ba.start2 + 8 * 32;  // 576

  // ---- iterate ----
  for (int it = 0; it < n_iters; ++it) {
    gemm_merged<<<fwdBlocks, 512, 0, stream>>>(fa);
    gemm_merged<<<bwdBlocks, 512, 0, stream>>>(ba);
  }
  // final prediction/error pass + e0 = mu0
  gemm_merged<<<fwdBlocks, 512, 0, stream>>>(faF);
  copy_e0<<<(512 * 1024 + 255) / 256, 256, 0, stream>>>(mu0, out);
}

// Round 12
// 3157.870 us; speedup vs baseline: 2.2532x; 2.2532x over previous
//
#include <hip/hip_runtime.h>
#include <hip/hip_bf16.h>
#include <stdint.h>

typedef __hip_bfloat16 bf16_t;
typedef __attribute__((ext_vector_type(8))) short bf16x8;
typedef __attribute__((ext_vector_type(4))) float f32x4;

#define MU_DT 0.01f

__device__ inline void gload_lds16(const void* g, void* lds) {
  __builtin_amdgcn_global_load_lds((const __attribute__((address_space(1))) void*)g,
                                   (__attribute__((address_space(3))) void*)lds, 16, 0, 0);
}

// mode: 0 = forward tanh layer, 1 = forward identity (last) layer,
//       2 = backward layer 0 (e0 == mu0), 3 = backward layer >0
struct GemmLayer {
  const bf16_t* A;    // (512 x K) bf16, row-major
  const bf16_t* Bt;   // (N x K) bf16, row-major  ("B^T layout" operand)
  const float*  X;    // fwd: mu_{l+1} or img (512 x N); bwd: mu_l (512 x N)
  const float*  E;    // bwd l>0: e_l (512 x N); else unused
  float*        O1;   // fwd: e_{l+1} out (stride ostride); bwd: mu_l out (f32)
  bf16_t*       O2;   // fwd: G_l out (bf16, 512 x N); bwd: mub_l out (bf16)
  int K, N, ostride, mode;
};

struct Seg { int start; int layer; int tnBase; int tilesN; };

struct GemmArgs {
  GemmLayer L[3];
  Seg seg[4];   // seg[i].start ascending; seg[3] may be sentinel (1<<30)
};

// R12: 128x128 tile, BK=64, 8 waves (512 thr), wave = 64 rows x 32 cols
// (4x2 of 16x16x32). Rationale: both surviving models (per-CU staged-bytes
// @ ~20B/cy, and per-CU block-step latency) predict gains from the bigger
// tile: FLOP/staged-byte 42.7->64 (fwd 768->512MB), per-CU block-steps
// 128->64. LDS 64KiB -> 2 blocks/CU = 16 waves/CU (> R8's measured 12.5).
// Engine = R8 verbatim (proven): issue next-tile gload_lds FIRST, then
// ds_read+MFMA on current half, ONE __syncthreads per K-step. A through
// LDS (R11 proved direct-global A is 2.4x worse). 16-lane-cohort reads
// (conflict-free, unlike R7's 32-lane pattern).
//
// Makespan balance via dispatch ORDER (capacity 2/CU => CU c hosts ids c
// and c+256): heavies first so doubled CUs get heavy+light, not 2 heavies.
// Segments start at multiples of 8 with tn FASTEST (tilesN mult of 8 where
// possible) to keep B-panel sharers on one XCD (R5 regression guard).
__global__ __launch_bounds__(512) void gemm_merged(GemmArgs args) {
  __shared__ __align__(16) bf16_t As[2 * 128 * 64];   // 2 x 16 KiB
  __shared__ __align__(16) bf16_t Bs[2 * 128 * 64];   // 2 x 16 KiB

  const int bid = blockIdx.x;
  int s;
  if (bid >= args.seg[3].start)      s = 3;
  else if (bid >= args.seg[2].start) s = 2;
  else if (bid >= args.seg[1].start) s = 1;
  else                               s = 0;
  const Seg sg = args.seg[s];
  const GemmLayer Lr = args.L[sg.layer];
  const int local = bid - sg.start;
  const int tm = local / sg.tilesN;
  const int tn = sg.tnBase + local % sg.tilesN;
  const int K = Lr.K;
  const int rowBase = tm * 128;
  const int colBase = tn * 128;

  const int tid  = threadIdx.x;        // 0..511
  const int lane = tid & 63;
  const int wv   = tid >> 6;           // 0..7
  const int wrM  = wv >> 2;            // 0..1 -> 64-row band
  const int wcN  = wv & 3;             // 0..3 -> 32-col band
  const int lo   = lane & 15, hi = lane >> 4;

  f32x4 acc[4][2];
#pragma unroll
  for (int m = 0; m < 4; ++m)
#pragma unroll
    for (int n = 0; n < 2; ++n)
      acc[m][n] = f32x4{0.f, 0.f, 0.f, 0.f};

  char* AsB = (char*)As;   // halves at +0 / +16384
  char* BsB = (char*)Bs;   // halves at +0 / +16384

  // ---- staging precompute: per 16B-chunk c -> (row = c>>3, slot = c&7) ----
  // A tile 128x64 = 1024 chunks (2/thread); B tile same.
  const bf16_t* pA[2];
  const bf16_t* pB[2];
#pragma unroll
  for (int j = 0; j < 2; ++j) {
    const int c = j * 512 + tid;
    const int r = c >> 3, sw = (c & 7) ^ (r & 7);
    pA[j] = Lr.A  + (size_t)(rowBase + r) * K + sw * 8;
    pB[j] = Lr.Bt + (size_t)(colBase + r) * K + sw * 8;
  }

  // ---- read-side swizzled byte offsets (16-lane cohorts, conflict-free) ----
  int aoff[4][2], boff[2][2];
#pragma unroll
  for (int m = 0; m < 4; ++m) {
    const int row = wrM * 64 + m * 16 + lo;
#pragma unroll
    for (int kk = 0; kk < 2; ++kk)
      aoff[m][kk] = row * 128 + (((kk * 4 + hi) ^ (row & 7)) << 4);
  }
#pragma unroll
  for (int n = 0; n < 2; ++n) {
    const int row = wcN * 32 + n * 16 + lo;
#pragma unroll
    for (int kk = 0; kk < 2; ++kk)
      boff[n][kk] = row * 128 + (((kk * 4 + hi) ^ (row & 7)) << 4);
  }

  const int waveB = wv * 1024;
  const int nkt = K >> 6;   // 16..64

  // prologue: stage tile 0 into half 0 (4 loads/thread: 2 A + 2 B)
#pragma unroll
  for (int j = 0; j < 2; ++j) {
    gload_lds16(pA[j], AsB + j * 8192 + waveB);
    gload_lds16(pB[j], BsB + j * 8192 + waveB);
  }
  __syncthreads();

  int cur = 0;   // byte offset of current half (0 / 16384)
  for (int kt = 0; kt < nkt; ++kt) {
    if (kt + 1 < nkt) {
      const int ke = (kt + 1) * 64;
      const int nxt = cur ^ 16384;
#pragma unroll
      for (int j = 0; j < 2; ++j) {
        gload_lds16(pA[j] + ke, AsB + nxt + j * 8192 + waveB);
        gload_lds16(pB[j] + ke, BsB + nxt + j * 8192 + waveB);
      }
    }

    bf16x8 a[4][2], b[2][2];
#pragma unroll
    for (int m = 0; m < 4; ++m)
#pragma unroll
      for (int kk = 0; kk < 2; ++kk)
        a[m][kk] = *(const bf16x8*)(AsB + cur + aoff[m][kk]);
#pragma unroll
    for (int n = 0; n < 2; ++n)
#pragma unroll
      for (int kk = 0; kk < 2; ++kk)
        b[n][kk] = *(const bf16x8*)(BsB + cur + boff[n][kk]);

#pragma unroll
    for (int kk = 0; kk < 2; ++kk)
#pragma unroll
      for (int m = 0; m < 4; ++m)
#pragma unroll
        for (int n = 0; n < 2; ++n)
          acc[m][n] = __builtin_amdgcn_mfma_f32_16x16x32_bf16(a[m][kk], b[n][kk], acc[m][n], 0, 0, 0);

    if (kt + 1 < nkt) {
      __syncthreads();   // drains vmcnt (next tile) + lgkm; one barrier per K-step
      cur ^= 16384;
    }
  }

  // epilogue — C/D layout: col = lane&15, row = (lane>>4)*4 + reg
  const int N = Lr.N;
#pragma unroll
  for (int m = 0; m < 4; ++m) {
#pragma unroll
    for (int n = 0; n < 2; ++n) {
#pragma unroll
      for (int r = 0; r < 4; ++r) {
        const int row = rowBase + wrM * 64 + m * 16 + hi * 4 + r;
        const int col = colBase + wcN * 32 + n * 16 + lo;
        const float v = acc[m][n][r];
        const size_t iN = (size_t)row * N + col;
        const size_t iO = (size_t)row * Lr.ostride + col;
        if (Lr.mode == 0) {
          const float mu = Lr.X[iN];
          const float t  = tanhf(v);
          const float e  = mu - t;
          Lr.O1[iO] = e;
          Lr.O2[iN] = __float2bfloat16(e * (1.0f - t * t));
        } else if (Lr.mode == 1) {
          const float e = Lr.X[iN] - v;
          Lr.O1[iO] = e;
          Lr.O2[iN] = __float2bfloat16(e);
        } else if (Lr.mode == 2) {
          const float mu = Lr.X[iN];
          const float nv = mu + MU_DT * (v - mu);
          Lr.O1[iN] = nv;
          Lr.O2[iN] = __float2bfloat16(nv);
        } else {
          const float mu = Lr.X[iN];
          const float e  = Lr.E[iN];
          const float nv = mu + MU_DT * (v - e);
          Lr.O1[iN] = nv;
          Lr.O2[iN] = __float2bfloat16(nv);
        }
      }
    }
  }
}

// convert W (R x C f32) -> Wb (R x C bf16) and WTb (C x R bf16)
__global__ void prep_weight(const float* __restrict__ W, bf16_t* __restrict__ Wb,
                            bf16_t* __restrict__ WTb, int R, int C) {
  __shared__ bf16_t t[64][65];
  const int tx = threadIdx.x, ty = threadIdx.y;  // (64,4)
  const int c0 = blockIdx.x * 64, r0 = blockIdx.y * 64;
  for (int rr = ty; rr < 64; rr += 4) {
    const float v = W[(size_t)(r0 + rr) * C + c0 + tx];
    const bf16_t b = __float2bfloat16(v);
    Wb[(size_t)(r0 + rr) * C + c0 + tx] = b;
    t[rr][tx] = b;
  }
  __syncthreads();
  for (int rr = ty; rr < 64; rr += 4) {
    WTb[(size_t)(c0 + rr) * R + r0 + tx] = t[tx][rr];
  }
}

__global__ void copy_cast(const float* __restrict__ in, float* __restrict__ of,
                          bf16_t* __restrict__ ob, int n) {
  const int i = blockIdx.x * blockDim.x + threadIdx.x;
  if (i < n) {
    const float v = in[i];
    of[i] = v;
    ob[i] = __float2bfloat16(v);
  }
}

__global__ void copy_e0(const float* __restrict__ mu0, float* __restrict__ out) {
  const int i = blockIdx.x * blockDim.x + threadIdx.x;
  if (i < 512 * 1024) {
    const int b = i >> 10, j = i & 1023;
    out[(size_t)b * 12288 + j] = mu0[i];
  }
}

extern "C" void kernel_launch(void* const* d_in, const int* in_sizes, int n_in,
                              void* d_out, int out_size, void* d_ws, size_t ws_size,
                              hipStream_t stream) {
  const float* img  = (const float*)d_in[0];
  const float* mu0i = (const float*)d_in[1];
  const float* mu1i = (const float*)d_in[2];
  const float* mu2i = (const float*)d_in[3];
  const float* W0   = (const float*)d_in[4];
  const float* W1   = (const float*)d_in[5];
  const float* W2   = (const float*)d_in[6];
  float* out = (float*)d_out;
  const int n_iters = 20;  // fixed by setup_inputs

  // ---- workspace carve (all offsets 256B aligned) ----
  char* p = (char*)d_ws;
  auto alloc = [&](size_t bytes) -> char* {
    char* r = p;
    p += (bytes + 255) & ~(size_t)255;
    return r;
  };
  bf16_t* Wb0 = (bf16_t*)alloc((size_t)1024 * 4096 * 2);
  bf16_t* Wb1 = (bf16_t*)alloc((size_t)4096 * 4096 * 2);
  bf16_t* Wb2 = (bf16_t*)alloc((size_t)4096 * 3072 * 2);
  bf16_t* WT0 = (bf16_t*)alloc((size_t)4096 * 1024 * 2);
  bf16_t* WT1 = (bf16_t*)alloc((size_t)4096 * 4096 * 2);
  bf16_t* WT2 = (bf16_t*)alloc((size_t)3072 * 4096 * 2);
  float*  mu0 = (float*)alloc((size_t)512 * 1024 * 4);
  float*  mu1 = (float*)alloc((size_t)512 * 4096 * 4);
  float*  mu2 = (float*)alloc((size_t)512 * 4096 * 4);
  bf16_t* mb0 = (bf16_t*)alloc((size_t)512 * 1024 * 2);
  bf16_t* mb1 = (bf16_t*)alloc((size_t)512 * 4096 * 2);
  bf16_t* mb2 = (bf16_t*)alloc((size_t)512 * 4096 * 2);
  float*  e1  = (float*)alloc((size_t)512 * 4096 * 4);
  float*  e2  = (float*)alloc((size_t)512 * 4096 * 4);
  float*  e3  = (float*)alloc((size_t)512 * 3072 * 4);
  bf16_t* G0  = (bf16_t*)alloc((size_t)512 * 4096 * 2);
  bf16_t* G1  = (bf16_t*)alloc((size_t)512 * 4096 * 2);
  bf16_t* G2  = (bf16_t*)alloc((size_t)512 * 3072 * 2);
  (void)ws_size;

  // ---- prep: weights + mus ----
  dim3 tb(64, 4);
  prep_weight<<<dim3(4096 / 64, 1024 / 64), tb, 0, stream>>>(W0, Wb0, WT0, 1024, 4096);
  prep_weight<<<dim3(4096 / 64, 4096 / 64), tb, 0, stream>>>(W1, Wb1, WT1, 4096, 4096);
  prep_weight<<<dim3(3072 / 64, 4096 / 64), tb, 0, stream>>>(W2, Wb2, WT2, 4096, 3072);
  copy_cast<<<(512 * 1024 + 255) / 256, 256, 0, stream>>>(mu0i, mu0, mb0, 512 * 1024);
  copy_cast<<<(512 * 4096 + 255) / 256, 256, 0, stream>>>(mu1i, mu1, mb1, 512 * 4096);
  copy_cast<<<(512 * 4096 + 255) / 256, 256, 0, stream>>>(mu2i, mu2, mb2, 512 * 4096);

  // ---- GEMM argument blocks (BM=128 -> 4 M-tiles, BN=128) ----
  // forward layers: L0: K=1024,N=4096 (light, 16 steps); L1: 4096,4096;
  // L2: 4096,3072. Heavy-first order: L1 ids 0..127, L2 128..223,
  // L0 224..351 -> doubled CUs (c<96) get heavy+light.
  GemmArgs fa;
  fa.L[0] = { mb0, WT0, mu1, nullptr, e1, G0, 1024, 4096, 4096, 0 };
  fa.L[1] = { mb1, WT1, mu2, nullptr, e2, G1, 4096, 4096, 4096, 0 };
  fa.L[2] = { mb2, WT2, img, nullptr, e3, G2, 4096, 3072, 3072, 1 };
  fa.seg[0] = { 0,   1, 0, 32 };   // L1: 4x32 = 128
  fa.seg[1] = { 128, 2, 0, 24 };   // L2: 4x24 = 96
  fa.seg[2] = { 224, 0, 0, 32 };   // L0: 4x32 = 128
  fa.seg[3] = { 1 << 30, 0, 0, 1 };
  const int fwdBlocks = 352;

  GemmArgs faF = fa;  // final pass: write errs straight into d_out (stride 12288)
  faF.L[0].O1 = out + 1024; faF.L[0].ostride = 12288;
  faF.L[1].O1 = out + 5120; faF.L[1].ostride = 12288;
  faF.L[2].O1 = out + 9216; faF.L[2].ostride = 12288;

  // backward layers: L0: K=4096,N=1024 (heavy); L1: 4096,4096 (heavy);
  // L2: K=3072,N=4096 (1.5MB). Order so doubled CUs (c<32) get L2+L2:
  // L2a (tn 0..7) ids 0..31; L1 ids 32..159; L0 ids 160..191;
  // L2b (tn 8..31) ids 192..287 (ids 256..287 pair with ids 0..31).
  GemmArgs ba;
  ba.L[0] = { G0, Wb0, mu0, nullptr, mu0, mb0, 4096, 1024, 1024, 2 };
  ba.L[1] = { G1, Wb1, mu1, e1,      mu1, mb1, 4096, 4096, 4096, 3 };
  ba.L[2] = { G2, Wb2, mu2, e2,      mu2, mb2, 3072, 4096, 4096, 3 };
  ba.seg[0] = { 0,   2, 0, 8 };    // L2a: 4x8  = 32
  ba.seg[1] = { 32,  1, 0, 32 };   // L1:  4x32 = 128
  ba.seg[2] = { 160, 0, 0, 8 };    // L0:  4x8  = 32
  ba.seg[3] = { 192, 2, 8, 24 };   // L2b: 4x24 = 96
  const int bwdBlocks = 288;

  // ---- iterate ----
  for (int it = 0; it < n_iters; ++it) {
    gemm_merged<<<fwdBlocks, 512, 0, stream>>>(fa);
    gemm_merged<<<bwdBlocks, 512, 0, stream>>>(ba);
  }
  // final prediction/error pass + e0 = mu0
  gemm_merged<<<fwdBlocks, 512, 0, stream>>>(faF);
  copy_e0<<<(512 * 1024 + 255) / 256, 256, 0, stream>>>(mu0, out);
}